// Round 2
// baseline (210.530 us; speedup 1.0000x reference)
//
#include <hip/hip_runtime.h>

// MHA fused forward: B=2,S=2048,D=1024,H=16,DK=64, causal, scores *= 8.
// Pipeline: cvt(fp32->fp16) -> 3x proj GEMM (fused, grid.z) -> flash attn -> out GEMM.
// fp16 (not bf16): 10 mantissa bits needed because scores = 8 * dot64 amplifies
// input rounding noise ~46x; bf16 gave absmax 0.084 > 0.0434 threshold.
// MFMA 16x16x32 f16 layouts (dtype-independent, learn_hip verified):
//   A: lane l holds A[row=l&15][k=(l>>4)*8 + j], j=0..7 (one b128 from row-major K-contig LDS)
//   B: lane l holds B[k=(l>>4)*8 + j][col=l&15]
//   C/D: reg r holds C[row=(l>>4)*4 + r][col=l&15]

typedef float f32x4 __attribute__((ext_vector_type(4)));
typedef unsigned int u32x4 __attribute__((ext_vector_type(4)));

#define DEV static __device__ __forceinline__

DEV unsigned short f2h(float x) {
  _Float16 h = (_Float16)x;   // v_cvt_f16_f32, RNE
  union { _Float16 h; unsigned short u; } v; v.h = h;
  return v.u;
}

DEV void mfma16(f32x4& d, u32x4 a, u32x4 b) {
  asm("v_mfma_f32_16x16x32_f16 %0, %1, %2, %0" : "+v"(d) : "v"(a), "v"(b));
}

DEV void gload16(const void* g, void* l) {
  __builtin_amdgcn_global_load_lds(
      (const __attribute__((address_space(1))) unsigned int*)g,
      (__attribute__((address_space(3))) unsigned int*)l, 16, 0, 0);
}

// MFMA(asm)->VALU read hazard guards (compiler can't see inside asm)
#define NOPG(a,b,c,d)  asm volatile("s_nop 7\n\ts_nop 7" : "+v"(a), "+v"(b), "+v"(c), "+v"(d))
#define NOPG1(a,b,c,d) asm volatile("s_nop 1" : "+v"(a), "+v"(b), "+v"(c), "+v"(d))

// ---------------- fp32 -> fp16 convert (k,q,v,wk,wq,wv,wo), 16.78M elements ----
__global__ __launch_bounds__(256) void cvt_all(
    const float* __restrict__ k, const float* __restrict__ q, const float* __restrict__ v,
    const float* __restrict__ wk, const float* __restrict__ wq, const float* __restrict__ wv,
    const float* __restrict__ wo, unsigned short* __restrict__ dst) {
  const int i = (blockIdx.x * 256 + threadIdx.x) * 4;  // element idx, < 16777216
  const float* src; int off;
  if (i < 4194304)       { src = k;  off = 0; }
  else if (i < 8388608)  { src = q;  off = 4194304; }
  else if (i < 12582912) { src = v;  off = 8388608; }
  else if (i < 13631488) { src = wk; off = 12582912; }
  else if (i < 14680064) { src = wq; off = 13631488; }
  else if (i < 15728640) { src = wv; off = 14680064; }
  else                   { src = wo; off = 15728640; }
  float4 val = *(const float4*)(src + (i - off));
  ushort4 o;
  o.x = f2h(val.x); o.y = f2h(val.y); o.z = f2h(val.z); o.w = f2h(val.w);
  *(ushort4*)(dst + i) = o;
}

// ---------------- NT GEMM 128x128 tile, BK=32, M=4096,N=1024,K=1024 -----------
// mode 0: fp16 out [B,H,S,64] ; mode 1: fp16 out [B,H,64,S] (V^T) ; mode 2: fp32 [M,N]
DEV void gemm_body(const unsigned short* __restrict__ A, const unsigned short* __restrict__ W,
                   const float* __restrict__ bias, void* __restrict__ out, int mode) {
  __shared__ alignas(16) char lds_a[8192];
  __shared__ alignas(16) char lds_b[8192];
  const int t = threadIdx.x;
  const int l = t & 63, g = l >> 4, c = l & 15, w = t >> 6;
  const int wr = w >> 1, wc = w & 1;
  const int m0 = blockIdx.y << 7, n0 = blockIdx.x << 7;

  f32x4 acc[4][4] = {};

  // staging: tile row = 64B = 4x16B slots; swizzle slot ^= (row&3)
  const int i0 = t, i1 = t + 256;
  const int ar0 = i0 >> 2, as0 = (i0 & 3) ^ (ar0 & 3);
  const int ar1 = i1 >> 2, as1 = (i1 & 3) ^ (ar1 & 3);
  const unsigned short* ga0 = A + (long)(m0 + ar0) * 1024 + as0 * 8;
  const unsigned short* ga1 = A + (long)(m0 + ar1) * 1024 + as1 * 8;
  const unsigned short* gb0 = W + (long)(n0 + ar0) * 1024 + as0 * 8;
  const unsigned short* gb1 = W + (long)(n0 + ar1) * 1024 + as1 * 8;
  char* la0 = lds_a + i0 * 16; char* la1 = lds_a + i1 * 16;
  char* lb0 = lds_b + i0 * 16; char* lb1 = lds_b + i1 * 16;

  int aoff[4], boff[4];
#pragma unroll
  for (int i = 0; i < 4; i++) {
    const int ra = (wr << 6) + (i << 4) + c;
    aoff[i] = ra * 64 + ((g << 4) ^ ((ra & 3) << 4));
    const int rb = (wc << 6) + (i << 4) + c;
    boff[i] = rb * 64 + ((g << 4) ^ ((rb & 3) << 4));
  }

  for (int kt = 0; kt < 32; kt++) {
    __syncthreads();
    gload16(ga0 + (kt << 5), la0);
    gload16(ga1 + (kt << 5), la1);
    gload16(gb0 + (kt << 5), lb0);
    gload16(gb1 + (kt << 5), lb1);
    __syncthreads();
    u32x4 af[4], bf[4];
#pragma unroll
    for (int i = 0; i < 4; i++) af[i] = *(const u32x4*)(lds_a + aoff[i]);
#pragma unroll
    for (int j = 0; j < 4; j++) bf[j] = *(const u32x4*)(lds_b + boff[j]);
#pragma unroll
    for (int i = 0; i < 4; i++)
#pragma unroll
      for (int j = 0; j < 4; j++)
        mfma16(acc[i][j], af[i], bf[j]);
  }

  NOPG(acc[0][0], acc[0][1], acc[0][2], acc[0][3]);
  NOPG(acc[1][0], acc[1][1], acc[1][2], acc[1][3]);
  NOPG(acc[2][0], acc[2][1], acc[2][2], acc[2][3]);
  NOPG(acc[3][0], acc[3][1], acc[3][2], acc[3][3]);

  if (mode == 1) {  // V^T layout: pack 4 consecutive s per lane -> 8B store
#pragma unroll
    for (int j = 0; j < 4; j++) {
      const int n = n0 + (wc << 6) + (j << 4) + c;
      const float bb = bias[n];
      const int h = n >> 6, d = n & 63;
#pragma unroll
      for (int i = 0; i < 4; i++) {
        const int m = m0 + (wr << 6) + (i << 4) + (g << 2);
        const int b = m >> 11, s = m & 2047;
        ushort4 o;
        o.x = f2h(acc[i][j][0] + bb);
        o.y = f2h(acc[i][j][1] + bb);
        o.z = f2h(acc[i][j][2] + bb);
        o.w = f2h(acc[i][j][3] + bb);
        *(ushort4*)&((unsigned short*)out)[((long)((b << 4) + h) * 64 + d) * 2048 + s] = o;
      }
    }
  } else {
#pragma unroll
    for (int j = 0; j < 4; j++) {
      const int n = n0 + (wc << 6) + (j << 4) + c;
      const float bb = bias[n];
#pragma unroll
      for (int i = 0; i < 4; i++) {
#pragma unroll
        for (int r = 0; r < 4; r++) {
          const int m = m0 + (wr << 6) + (i << 4) + (g << 2) + r;
          const float val = acc[i][j][r] + bb;
          if (mode == 2) {
            ((float*)out)[(long)m * 1024 + n] = val;
          } else {
            const int b = m >> 11, s = m & 2047;
            const int h = n >> 6, d = n & 63;
            ((unsigned short*)out)[((long)((b << 4) + h) * 2048 + s) * 64 + d] = f2h(val);
          }
        }
      }
    }
  }
}

__global__ __launch_bounds__(256) void gemm_proj(
    const unsigned short* kb, const unsigned short* qb, const unsigned short* vb,
    const unsigned short* wkb, const unsigned short* wqb, const unsigned short* wvb,
    const float* bk, const float* bq, const float* bvv,
    unsigned short* Kp, unsigned short* Qp, unsigned short* VpT) {
  const int z = blockIdx.z;
  const unsigned short* A = (z == 0) ? kb : (z == 1) ? qb : vb;
  const unsigned short* W = (z == 0) ? wkb : (z == 1) ? wqb : wvb;
  const float* bias = (z == 0) ? bk : (z == 1) ? bq : bvv;
  void* out = (z == 0) ? (void*)Kp : (z == 1) ? (void*)Qp : (void*)VpT;
  gemm_body(A, W, bias, out, (z == 2) ? 1 : 0);
}

__global__ __launch_bounds__(256) void gemm_out(
    const unsigned short* A, const unsigned short* W, const float* bias, float* out) {
  gemm_body(A, W, bias, out, 2);
}

// ---------------- flash attention: block=(qtile 64 rows, bh), 4 waves x 16 rows
__global__ __launch_bounds__(256) void attn_kernel(
    const unsigned short* __restrict__ Qp, const unsigned short* __restrict__ Kp,
    const unsigned short* __restrict__ VpT, unsigned short* __restrict__ O) {
  __shared__ alignas(16) char lds_k[8192];   // K tile [64 kv][64 d], swizzled
  __shared__ alignas(16) char lds_v[8192];   // V^T tile [64 d][64 kv], swizzled
  __shared__ alignas(16) char lds_p[8192];   // per-wave P [16 q][64 kv], swizzled

  const int t = threadIdx.x;
  const int l = t & 63, g = l >> 4, c = l & 15, w = t >> 6;
  const int bh = blockIdx.y;
  const int qt = 31 - blockIdx.x;            // longest tiles first
  const int q0 = qt << 6;
  const int qrow = q0 + (w << 4);

  const unsigned short* qbase = Qp + ((long)bh * 2048 + qrow + c) * 64 + g * 8;
  const u32x4 aq0 = *(const u32x4*)qbase;
  const u32x4 aq1 = *(const u32x4*)(qbase + 32);

  f32x4 oacc[4] = {};
  float mrun[4] = {-1e30f, -1e30f, -1e30f, -1e30f};
  float lrun[4] = {0.f, 0.f, 0.f, 0.f};

  // staging: 128B rows = 8x16B slots; swizzle slot ^= (row&7)
  const int i0 = t, i1 = t + 256;
  const int r0 = i0 >> 3, s0 = (i0 & 7) ^ (r0 & 7);
  const int r1 = i1 >> 3, s1 = (i1 & 7) ^ (r1 & 7);
  const unsigned short* gk0 = Kp + ((long)bh * 2048 + r0) * 64 + s0 * 8;
  const unsigned short* gk1 = Kp + ((long)bh * 2048 + r1) * 64 + s1 * 8;
  const unsigned short* gv0 = VpT + ((long)bh * 64 + r0) * 2048 + s0 * 8;
  const unsigned short* gv1 = VpT + ((long)bh * 64 + r1) * 2048 + s1 * 8;
  char* lk0 = lds_k + i0 * 16; char* lk1 = lds_k + i1 * 16;
  char* lv0 = lds_v + i0 * 16; char* lv1 = lds_v + i1 * 16;

  int koff[4][2];
#pragma unroll
  for (int j = 0; j < 4; j++)
#pragma unroll
    for (int ks = 0; ks < 2; ks++) {
      const int row = (j << 4) + c;
      koff[j][ks] = row * 128 + (((ks << 6) + (g << 4)) ^ ((row & 7) << 4));
    }
  const int poff0 = (w << 11) + c * 128 + (((g << 4)) ^ ((c & 7) << 4));
  const int poff1 = (w << 11) + c * 128 + ((64 + (g << 4)) ^ ((c & 7) << 4));

  const int ntiles = qt + 1;
  for (int tt = 0; tt < ntiles; tt++) {
    const int kv0 = tt << 6;
    __syncthreads();
    gload16(gk0 + (long)kv0 * 64, lk0);
    gload16(gk1 + (long)kv0 * 64, lk1);
    gload16(gv0 + kv0, lv0);
    gload16(gv1 + kv0, lv1);
    __syncthreads();

    f32x4 sacc[4] = {};
    NOPG1(sacc[0], sacc[1], sacc[2], sacc[3]);
#pragma unroll
    for (int j = 0; j < 4; j++) {
      u32x4 bk0 = *(const u32x4*)(lds_k + koff[j][0]);
      u32x4 bk1 = *(const u32x4*)(lds_k + koff[j][1]);
      mfma16(sacc[j], aq0, bk0);
      mfma16(sacc[j], aq1, bk1);
    }
    NOPG(sacc[0], sacc[1], sacc[2], sacc[3]);

#pragma unroll
    for (int r = 0; r < 4; r++) {
      const int qg = qrow + (g << 2) + r;
      float v0 = sacc[0][r] * 8.0f; if (kv0 + c      > qg) v0 = -1e30f;
      float v1 = sacc[1][r] * 8.0f; if (kv0 + 16 + c > qg) v1 = -1e30f;
      float v2 = sacc[2][r] * 8.0f; if (kv0 + 32 + c > qg) v2 = -1e30f;
      float v3 = sacc[3][r] * 8.0f; if (kv0 + 48 + c > qg) v3 = -1e30f;
      float mx = fmaxf(fmaxf(v0, v1), fmaxf(v2, v3));
      mx = fmaxf(mx, __shfl_xor(mx, 1));
      mx = fmaxf(mx, __shfl_xor(mx, 2));
      mx = fmaxf(mx, __shfl_xor(mx, 4));
      mx = fmaxf(mx, __shfl_xor(mx, 8));
      const float mnew = fmaxf(mrun[r], mx);
      const float corr = exp2f((mrun[r] - mnew) * 1.44269504f);
      const float p0 = exp2f((v0 - mnew) * 1.44269504f);
      const float p1 = exp2f((v1 - mnew) * 1.44269504f);
      const float p2 = exp2f((v2 - mnew) * 1.44269504f);
      const float p3 = exp2f((v3 - mnew) * 1.44269504f);
      float ps = p0 + p1 + p2 + p3;
      ps += __shfl_xor(ps, 1);
      ps += __shfl_xor(ps, 2);
      ps += __shfl_xor(ps, 4);
      ps += __shfl_xor(ps, 8);
      lrun[r] = lrun[r] * corr + ps;
      mrun[r] = mnew;
      oacc[0][r] *= corr; oacc[1][r] *= corr; oacc[2][r] *= corr; oacc[3][r] *= corr;
      const int prow = (g << 2) + r;
      char* pb = lds_p + (w << 11) + prow * 128;
      const int sw = (prow & 7) << 4;
      *(unsigned short*)(pb + (((c << 1)     ) ^ sw)) = f2h(p0);
      *(unsigned short*)(pb + (((c << 1) + 32) ^ sw)) = f2h(p1);
      *(unsigned short*)(pb + (((c << 1) + 64) ^ sw)) = f2h(p2);
      *(unsigned short*)(pb + (((c << 1) + 96) ^ sw)) = f2h(p3);
    }

    NOPG1(oacc[0], oacc[1], oacc[2], oacc[3]);
    u32x4 ap0 = *(const u32x4*)(lds_p + poff0);
    u32x4 ap1 = *(const u32x4*)(lds_p + poff1);
#pragma unroll
    for (int jd = 0; jd < 4; jd++) {
      u32x4 bv0 = *(const u32x4*)(lds_v + koff[jd][0]);
      u32x4 bv1 = *(const u32x4*)(lds_v + koff[jd][1]);
      mfma16(oacc[jd], ap0, bv0);
      mfma16(oacc[jd], ap1, bv1);
    }
  }

  NOPG(oacc[0], oacc[1], oacc[2], oacc[3]);
  const int b = bh >> 4, h = bh & 15;
#pragma unroll
  for (int r = 0; r < 4; r++) {
    const float inv = 1.0f / lrun[r];
    const long mrow = (long)b * 2048 + q0 + (w << 4) + (g << 2) + r;
#pragma unroll
    for (int jd = 0; jd < 4; jd++)
      O[mrow * 1024 + (h << 6) + (jd << 4) + c] = f2h(oacc[jd][r] * inv);
  }
}

// ---------------- launch ------------------------------------------------------
extern "C" void kernel_launch(void* const* d_in, const int* in_sizes, int n_in,
                              void* d_out, int out_size, void* d_ws, size_t ws_size,
                              hipStream_t stream) {
  (void)in_sizes; (void)n_in; (void)out_size; (void)ws_size;
  const float* kin = (const float*)d_in[0];
  const float* qin = (const float*)d_in[1];
  const float* vin = (const float*)d_in[2];
  const float* wk  = (const float*)d_in[4];
  const float* bk  = (const float*)d_in[5];
  const float* wq  = (const float*)d_in[6];
  const float* bq  = (const float*)d_in[7];
  const float* wv  = (const float*)d_in[8];
  const float* bv  = (const float*)d_in[9];
  const float* wo  = (const float*)d_in[10];
  const float* bo  = (const float*)d_in[11];

  unsigned short* ws  = (unsigned short*)d_ws;   // 64 MiB used
  unsigned short* kb  = ws;                       // fp16 inputs
  unsigned short* qb  = ws + 4194304;
  unsigned short* vb  = ws + 8388608;
  unsigned short* wkb = ws + 12582912;
  unsigned short* wqb = ws + 13631488;
  unsigned short* wvb = ws + 14680064;
  unsigned short* wob = ws + 15728640;
  unsigned short* Kp  = ws + 16777216;            // [B,H,S,64]
  unsigned short* Qp  = ws + 20971520;            // [B,H,S,64]
  unsigned short* VpT = ws + 25165824;            // [B,H,64,S]
  unsigned short* Oo  = ws + 29360128;            // [B,S,D]

  cvt_all<<<16384, 256, 0, stream>>>(kin, qin, vin, wk, wq, wv, wo, ws);
  gemm_proj<<<dim3(8, 32, 3), 256, 0, stream>>>(kb, qb, vb, wkb, wqb, wvb,
                                                bk, bq, bv, Kp, Qp, VpT);
  attn_kernel<<<dim3(32, 32), 256, 0, stream>>>(Qp, Kp, VpT, Oo);
  gemm_out<<<dim3(8, 32), 256, 0, stream>>>(Oo, wob, bo, (float*)d_out);
}

// Round 3
// 148.800 us; speedup vs baseline: 1.4149x; 1.4149x over previous
//
#include <hip/hip_runtime.h>

// MHA fused forward: B=2,S=2048,D=1024,H=16,DK=64, causal, scores *= 8.
// Pipeline: cvt(fp32->fp16) -> 3x proj GEMM (fused, grid.z) -> flash attn -> out GEMM.
// fp16 pipeline (bf16 failed precision: scores = 8*dot64 amplify rounding).
// Attn: paired q-tiles (qt=p and 31-p => 33 kv-tiles per block, perfectly balanced),
// double-buffered K/V staging with counted-vmcnt + single raw s_barrier per tile.
// Q is pre-scaled by 8*log2e in the projection epilogue => softmax uses exp2 directly.

typedef float f32x4 __attribute__((ext_vector_type(4)));
typedef unsigned int u32x4 __attribute__((ext_vector_type(4)));

#define DEV static __device__ __forceinline__

DEV unsigned short f2h(float x) {
  _Float16 h = (_Float16)x;   // v_cvt_f16_f32, RNE
  union { _Float16 h; unsigned short u; } v; v.h = h;
  return v.u;
}

DEV void mfma16(f32x4& d, u32x4 a, u32x4 b) {
  asm("v_mfma_f32_16x16x32_f16 %0, %1, %2, %0" : "+v"(d) : "v"(a), "v"(b));
}

DEV void gload16(const void* g, void* l) {
  __builtin_amdgcn_global_load_lds(
      (const __attribute__((address_space(1))) unsigned int*)g,
      (__attribute__((address_space(3))) unsigned int*)l, 16, 0, 0);
}

#define VMCNT0() asm volatile("s_waitcnt vmcnt(0)" ::: "memory")

// MFMA(asm)->VALU read hazard guards (compiler can't see inside asm)
#define NOPG(a,b,c,d)  asm volatile("s_nop 7\n\ts_nop 7" : "+v"(a), "+v"(b), "+v"(c), "+v"(d))
#define NOPG1(a,b,c,d) asm volatile("s_nop 1" : "+v"(a), "+v"(b), "+v"(c), "+v"(d))

// ---------------- fp32 -> fp16 convert (k,q,v,wk,wq,wv,wo), 16.78M elements ----
__global__ __launch_bounds__(256) void cvt_all(
    const float* __restrict__ k, const float* __restrict__ q, const float* __restrict__ v,
    const float* __restrict__ wk, const float* __restrict__ wq, const float* __restrict__ wv,
    const float* __restrict__ wo, unsigned short* __restrict__ dst) {
  const int i = (blockIdx.x * 256 + threadIdx.x) * 4;  // element idx, < 16777216
  const float* src; int off;
  if (i < 4194304)       { src = k;  off = 0; }
  else if (i < 8388608)  { src = q;  off = 4194304; }
  else if (i < 12582912) { src = v;  off = 8388608; }
  else if (i < 13631488) { src = wk; off = 12582912; }
  else if (i < 14680064) { src = wq; off = 13631488; }
  else if (i < 15728640) { src = wv; off = 14680064; }
  else                   { src = wo; off = 15728640; }
  float4 val = *(const float4*)(src + (i - off));
  ushort4 o;
  o.x = f2h(val.x); o.y = f2h(val.y); o.z = f2h(val.z); o.w = f2h(val.w);
  *(ushort4*)(dst + i) = o;
}

// ---------------- NT GEMM 128x128 tile, BK=32, M=4096,N=1024,K=1024 -----------
// Double-buffered LDS, counted vmcnt, one raw barrier per K-step.
// mode 0: fp16 out [B,H,S,64] (scaled) ; mode 1: fp16 out [B,H,64,S] (V^T) ; mode 2: fp32 [M,N]
DEV void gemm_body(const unsigned short* __restrict__ A, const unsigned short* __restrict__ W,
                   const float* __restrict__ bias, void* __restrict__ out, int mode,
                   float oscale) {
  __shared__ alignas(16) char lds_a[2][8192];
  __shared__ alignas(16) char lds_b[2][8192];
  const int t = threadIdx.x;
  const int l = t & 63, g = l >> 4, c = l & 15, w = t >> 6;
  const int wr = w >> 1, wc = w & 1;
  const int m0 = blockIdx.y << 7, n0 = blockIdx.x << 7;

  f32x4 acc[4][4] = {};

  // staging: tile row = 64B = 4x16B slots; swizzle slot ^= (row&3)
  const int i0 = t, i1 = t + 256;
  const int ar0 = i0 >> 2, as0 = (i0 & 3) ^ (ar0 & 3);
  const int ar1 = i1 >> 2, as1 = (i1 & 3) ^ (ar1 & 3);
  const unsigned short* ga0 = A + (long)(m0 + ar0) * 1024 + as0 * 8;
  const unsigned short* ga1 = A + (long)(m0 + ar1) * 1024 + as1 * 8;
  const unsigned short* gb0 = W + (long)(n0 + ar0) * 1024 + as0 * 8;
  const unsigned short* gb1 = W + (long)(n0 + ar1) * 1024 + as1 * 8;
  const int lo0 = i0 * 16, lo1 = i1 * 16;

  int aoff[4], boff[4];
#pragma unroll
  for (int i = 0; i < 4; i++) {
    const int ra = (wr << 6) + (i << 4) + c;
    aoff[i] = ra * 64 + ((g << 4) ^ ((ra & 3) << 4));
    const int rb = (wc << 6) + (i << 4) + c;
    boff[i] = rb * 64 + ((g << 4) ^ ((rb & 3) << 4));
  }

  // prologue: stage kt=0 into buf 0
  gload16(ga0, lds_a[0] + lo0);
  gload16(ga1, lds_a[0] + lo1);
  gload16(gb0, lds_b[0] + lo0);
  gload16(gb1, lds_b[0] + lo1);

  for (int kt = 0; kt < 32; kt++) {
    const int cur = kt & 1;
    VMCNT0();                       // own buf[cur] loads landed (issued last iter)
    __builtin_amdgcn_s_barrier();   // everyone's landed; everyone done with buf[cur^1]
    if (kt + 1 < 32) {
      gload16(ga0 + ((kt + 1) << 5), lds_a[cur ^ 1] + lo0);
      gload16(ga1 + ((kt + 1) << 5), lds_a[cur ^ 1] + lo1);
      gload16(gb0 + ((kt + 1) << 5), lds_b[cur ^ 1] + lo0);
      gload16(gb1 + ((kt + 1) << 5), lds_b[cur ^ 1] + lo1);
    }
    u32x4 af[4], bf[4];
#pragma unroll
    for (int i = 0; i < 4; i++) af[i] = *(const u32x4*)(lds_a[cur] + aoff[i]);
#pragma unroll
    for (int j = 0; j < 4; j++) bf[j] = *(const u32x4*)(lds_b[cur] + boff[j]);
#pragma unroll
    for (int i = 0; i < 4; i++)
#pragma unroll
      for (int j = 0; j < 4; j++)
        mfma16(acc[i][j], af[i], bf[j]);
  }

  NOPG(acc[0][0], acc[0][1], acc[0][2], acc[0][3]);
  NOPG(acc[1][0], acc[1][1], acc[1][2], acc[1][3]);
  NOPG(acc[2][0], acc[2][1], acc[2][2], acc[2][3]);
  NOPG(acc[3][0], acc[3][1], acc[3][2], acc[3][3]);

  if (mode == 1) {  // V^T layout: pack 4 consecutive s per lane -> 8B store
#pragma unroll
    for (int j = 0; j < 4; j++) {
      const int n = n0 + (wc << 6) + (j << 4) + c;
      const float bb = bias[n];
      const int h = n >> 6, d = n & 63;
#pragma unroll
      for (int i = 0; i < 4; i++) {
        const int m = m0 + (wr << 6) + (i << 4) + (g << 2);
        const int b = m >> 11, s = m & 2047;
        ushort4 o;
        o.x = f2h(acc[i][j][0] + bb);
        o.y = f2h(acc[i][j][1] + bb);
        o.z = f2h(acc[i][j][2] + bb);
        o.w = f2h(acc[i][j][3] + bb);
        *(ushort4*)&((unsigned short*)out)[((long)((b << 4) + h) * 64 + d) * 2048 + s] = o;
      }
    }
  } else {
#pragma unroll
    for (int j = 0; j < 4; j++) {
      const int n = n0 + (wc << 6) + (j << 4) + c;
      const float bb = bias[n];
#pragma unroll
      for (int i = 0; i < 4; i++) {
#pragma unroll
        for (int r = 0; r < 4; r++) {
          const int m = m0 + (wr << 6) + (i << 4) + (g << 2) + r;
          const float val = (acc[i][j][r] + bb) * oscale;
          if (mode == 2) {
            ((float*)out)[(long)m * 1024 + n] = val;
          } else {
            const int b = m >> 11, s = m & 2047;
            const int h = n >> 6, d = n & 63;
            ((unsigned short*)out)[((long)((b << 4) + h) * 2048 + s) * 64 + d] = f2h(val);
          }
        }
      }
    }
  }
}

__global__ __launch_bounds__(256) void gemm_proj(
    const unsigned short* kb, const unsigned short* qb, const unsigned short* vb,
    const unsigned short* wkb, const unsigned short* wqb, const unsigned short* wvb,
    const float* bk, const float* bq, const float* bvv,
    unsigned short* Kp, unsigned short* Qp, unsigned short* VpT) {
  const int z = blockIdx.z;
  const unsigned short* A = (z == 0) ? kb : (z == 1) ? qb : vb;
  const unsigned short* W = (z == 0) ? wkb : (z == 1) ? wqb : wvb;
  const float* bias = (z == 0) ? bk : (z == 1) ? bq : bvv;
  void* out = (z == 0) ? (void*)Kp : (z == 1) ? (void*)Qp : (void*)VpT;
  // Q pre-scaled by 8*log2(e): softmax then uses exp2(s - m) with no per-score muls.
  const float sc = (z == 1) ? 11.5415603271f : 1.0f;
  gemm_body(A, W, bias, out, (z == 2) ? 1 : 0, sc);
}

__global__ __launch_bounds__(256) void gemm_out(
    const unsigned short* A, const unsigned short* W, const float* bias, float* out) {
  gemm_body(A, W, bias, out, 2, 1.0f);
}

// ---------------- flash attention ---------------------------------------------
// Block p handles q-tiles {p, 31-p}: 33 kv-tile iterations for every block.
// K/V double-buffered; 1 raw barrier + counted vmcnt per tile iteration.
__global__ __launch_bounds__(256) void attn_kernel(
    const unsigned short* __restrict__ Qp, const unsigned short* __restrict__ Kp,
    const unsigned short* __restrict__ VpT, unsigned short* __restrict__ O) {
  __shared__ alignas(16) char lds_k[2][8192];  // K tile [64 kv][64 d], swizzled
  __shared__ alignas(16) char lds_v[2][8192];  // V^T tile [64 d][64 kv], swizzled
  __shared__ alignas(16) char lds_p[8192];     // per-wave P [16 q][64 kv], swizzled

  const int t = threadIdx.x;
  const int l = t & 63, g = l >> 4, c = l & 15, w = t >> 6;
  const int bh = blockIdx.y;

  // staging: 128B rows = 8x16B slots; swizzle slot ^= (row&7)
  const int i0 = t, i1 = t + 256;
  const int r0 = i0 >> 3, s0 = (i0 & 7) ^ (r0 & 7);
  const int r1 = i1 >> 3, s1 = (i1 & 7) ^ (r1 & 7);
  const unsigned short* gk0 = Kp + ((long)bh * 2048 + r0) * 64 + s0 * 8;
  const unsigned short* gk1 = Kp + ((long)bh * 2048 + r1) * 64 + s1 * 8;
  const unsigned short* gv0 = VpT + ((long)bh * 64 + r0) * 2048 + s0 * 8;
  const unsigned short* gv1 = VpT + ((long)bh * 64 + r1) * 2048 + s1 * 8;
  const int lo0 = i0 * 16, lo1 = i1 * 16;

  int koff[4][2];
#pragma unroll
  for (int j = 0; j < 4; j++)
#pragma unroll
    for (int ks = 0; ks < 2; ks++) {
      const int row = (j << 4) + c;
      koff[j][ks] = row * 128 + (((ks << 6) + (g << 4)) ^ ((row & 7) << 4));
    }
  const int poff0 = (w << 11) + c * 128 + (((g << 4)) ^ ((c & 7) << 4));
  const int poff1 = (w << 11) + c * 128 + ((64 + (g << 4)) ^ ((c & 7) << 4));

  const int b = bh >> 4, h = bh & 15;

#pragma unroll 1
  for (int half = 0; half < 2; half++) {
    const int qt = half ? (31 - (int)blockIdx.x) : (int)blockIdx.x;
    const int q0 = qt << 6;
    const int qrow = q0 + (w << 4);

    const unsigned short* qbase = Qp + ((long)bh * 2048 + qrow + c) * 64 + g * 8;
    const u32x4 aq0 = *(const u32x4*)qbase;
    const u32x4 aq1 = *(const u32x4*)(qbase + 32);

    f32x4 oacc[4] = {};
    float mrun[4] = {-1e30f, -1e30f, -1e30f, -1e30f};
    float lrun[4] = {0.f, 0.f, 0.f, 0.f};

    const int ntiles = qt + 1;

    // protect buf0 from any wave still reading it (prev half), then prologue-stage
    __builtin_amdgcn_s_barrier();
    gload16(gk0, lds_k[0] + lo0);
    gload16(gk1, lds_k[0] + lo1);
    gload16(gv0, lds_v[0] + lo0);
    gload16(gv1, lds_v[0] + lo1);

    for (int tt = 0; tt < ntiles; tt++) {
      const int cur = tt & 1;
      VMCNT0();                       // own buf[cur] loads landed
      __builtin_amdgcn_s_barrier();   // all landed; all done reading buf[cur^1]
      if (tt + 1 < ntiles) {
        const long kvn = (long)(tt + 1) << 6;
        gload16(gk0 + kvn * 64, lds_k[cur ^ 1] + lo0);
        gload16(gk1 + kvn * 64, lds_k[cur ^ 1] + lo1);
        gload16(gv0 + kvn,      lds_v[cur ^ 1] + lo0);
        gload16(gv1 + kvn,      lds_v[cur ^ 1] + lo1);
      }

      f32x4 sacc[4] = {};
      NOPG1(sacc[0], sacc[1], sacc[2], sacc[3]);
#pragma unroll
      for (int j = 0; j < 4; j++) {
        u32x4 bk0 = *(const u32x4*)(lds_k[cur] + koff[j][0]);
        u32x4 bk1 = *(const u32x4*)(lds_k[cur] + koff[j][1]);
        mfma16(sacc[j], aq0, bk0);
        mfma16(sacc[j], aq1, bk1);
      }
      NOPG(sacc[0], sacc[1], sacc[2], sacc[3]);

      const int kv0 = tt << 6;
      const bool diag = (tt == qt);
#pragma unroll
      for (int r = 0; r < 4; r++) {
        float v0 = sacc[0][r];
        float v1 = sacc[1][r];
        float v2 = sacc[2][r];
        float v3 = sacc[3][r];
        if (diag) {                   // uniform branch: causal mask, diagonal tile only
          const int qg = qrow + (g << 2) + r;
          if (kv0 + c      > qg) v0 = -1e30f;
          if (kv0 + 16 + c > qg) v1 = -1e30f;
          if (kv0 + 32 + c > qg) v2 = -1e30f;
          if (kv0 + 48 + c > qg) v3 = -1e30f;
        }
        float mx = fmaxf(fmaxf(v0, v1), fmaxf(v2, v3));
        mx = fmaxf(mx, __shfl_xor(mx, 1));
        mx = fmaxf(mx, __shfl_xor(mx, 2));
        mx = fmaxf(mx, __shfl_xor(mx, 4));
        mx = fmaxf(mx, __shfl_xor(mx, 8));
        const float mnew = fmaxf(mrun[r], mx);
        const float corr = exp2f(mrun[r] - mnew);
        const float p0 = exp2f(v0 - mnew);
        const float p1 = exp2f(v1 - mnew);
        const float p2 = exp2f(v2 - mnew);
        const float p3 = exp2f(v3 - mnew);
        lrun[r] = lrun[r] * corr + (p0 + p1 + p2 + p3);   // per-lane partial; reduce at end
        mrun[r] = mnew;
        oacc[0][r] *= corr; oacc[1][r] *= corr; oacc[2][r] *= corr; oacc[3][r] *= corr;
        const int prow = (g << 2) + r;
        char* pb = lds_p + (w << 11) + prow * 128;
        const int sw = (prow & 7) << 4;
        *(unsigned short*)(pb + (((c << 1)     ) ^ sw)) = f2h(p0);
        *(unsigned short*)(pb + (((c << 1) + 32) ^ sw)) = f2h(p1);
        *(unsigned short*)(pb + (((c << 1) + 64) ^ sw)) = f2h(p2);
        *(unsigned short*)(pb + (((c << 1) + 96) ^ sw)) = f2h(p3);
      }

      NOPG1(oacc[0], oacc[1], oacc[2], oacc[3]);
      u32x4 ap0 = *(const u32x4*)(lds_p + poff0);
      u32x4 ap1 = *(const u32x4*)(lds_p + poff1);
#pragma unroll
      for (int jd = 0; jd < 4; jd++) {
        u32x4 bv0 = *(const u32x4*)(lds_v[cur] + koff[jd][0]);
        u32x4 bv1 = *(const u32x4*)(lds_v[cur] + koff[jd][1]);
        mfma16(oacc[jd], ap0, bv0);
        mfma16(oacc[jd], ap1, bv1);
      }
    }

    NOPG(oacc[0], oacc[1], oacc[2], oacc[3]);
#pragma unroll
    for (int r = 0; r < 4; r++) {
      float lsum = lrun[r];
      lsum += __shfl_xor(lsum, 1);
      lsum += __shfl_xor(lsum, 2);
      lsum += __shfl_xor(lsum, 4);
      lsum += __shfl_xor(lsum, 8);
      const float inv = 1.0f / lsum;
      const long mrow = (long)b * 2048 + q0 + (w << 4) + (g << 2) + r;
#pragma unroll
      for (int jd = 0; jd < 4; jd++)
        O[mrow * 1024 + (h << 6) + (jd << 4) + c] = f2h(oacc[jd][r] * inv);
    }
  }
}

// ---------------- launch ------------------------------------------------------
extern "C" void kernel_launch(void* const* d_in, const int* in_sizes, int n_in,
                              void* d_out, int out_size, void* d_ws, size_t ws_size,
                              hipStream_t stream) {
  (void)in_sizes; (void)n_in; (void)out_size; (void)ws_size;
  const float* kin = (const float*)d_in[0];
  const float* qin = (const float*)d_in[1];
  const float* vin = (const float*)d_in[2];
  const float* wk  = (const float*)d_in[4];
  const float* bk  = (const float*)d_in[5];
  const float* wq  = (const float*)d_in[6];
  const float* bq  = (const float*)d_in[7];
  const float* wv  = (const float*)d_in[8];
  const float* bv  = (const float*)d_in[9];
  const float* wo  = (const float*)d_in[10];
  const float* bo  = (const float*)d_in[11];

  unsigned short* ws  = (unsigned short*)d_ws;   // 64 MiB used
  unsigned short* kb  = ws;                       // fp16 inputs
  unsigned short* qb  = ws + 4194304;
  unsigned short* vb  = ws + 8388608;
  unsigned short* wkb = ws + 12582912;
  unsigned short* wqb = ws + 13631488;
  unsigned short* wvb = ws + 14680064;
  unsigned short* wob = ws + 15728640;
  unsigned short* Kp  = ws + 16777216;            // [B,H,S,64]
  unsigned short* Qp  = ws + 20971520;            // [B,H,S,64], pre-scaled by 8*log2e
  unsigned short* VpT = ws + 25165824;            // [B,H,64,S]
  unsigned short* Oo  = ws + 29360128;            // [B,S,D]

  cvt_all<<<16384, 256, 0, stream>>>(kin, qin, vin, wk, wq, wv, wo, ws);
  gemm_proj<<<dim3(8, 32, 3), 256, 0, stream>>>(kb, qb, vb, wkb, wqb, wvb,
                                                bk, bq, bv, Kp, Qp, VpT);
  attn_kernel<<<dim3(16, 32), 256, 0, stream>>>(Qp, Kp, VpT, Oo);
  gemm_out<<<dim3(8, 32), 256, 0, stream>>>(Oo, wob, bo, (float*)d_out);
}

// Round 4
// 140.854 us; speedup vs baseline: 1.4947x; 1.0564x over previous
//
#include <hip/hip_runtime.h>

// MHA fused forward: B=2,S=2048,D=1024,H=16,DK=64, causal, scores *= 8.
// Pipeline: cvt(fp32->fp16) -> 3x proj GEMM (fused, grid.z) -> flash attn -> out GEMM.
// fp16 pipeline (bf16 failed precision: scores = 8*dot64 amplify rounding).
// Attn R4: one q-tile per block, 1024 blocks (4/CU, 50% occ cap), global
// longest-first dispatch (LPT backfill); dbuf K/V + counted vmcnt + 1 barrier/tile;
// s_setprio(1) around MFMA clusters. Q pre-scaled by 8*log2e => exp2 softmax.

typedef float f32x4 __attribute__((ext_vector_type(4)));
typedef unsigned int u32x4 __attribute__((ext_vector_type(4)));

#define DEV static __device__ __forceinline__

DEV unsigned short f2h(float x) {
  _Float16 h = (_Float16)x;   // v_cvt_f16_f32, RNE
  union { _Float16 h; unsigned short u; } v; v.h = h;
  return v.u;
}

DEV void mfma16(f32x4& d, u32x4 a, u32x4 b) {
  asm("v_mfma_f32_16x16x32_f16 %0, %1, %2, %0" : "+v"(d) : "v"(a), "v"(b));
}

DEV void gload16(const void* g, void* l) {
  __builtin_amdgcn_global_load_lds(
      (const __attribute__((address_space(1))) unsigned int*)g,
      (__attribute__((address_space(3))) unsigned int*)l, 16, 0, 0);
}

#define VMCNT0() asm volatile("s_waitcnt vmcnt(0)" ::: "memory")

// MFMA(asm)->VALU read hazard guards (compiler can't see inside asm)
#define NOPG(a,b,c,d)  asm volatile("s_nop 7\n\ts_nop 7" : "+v"(a), "+v"(b), "+v"(c), "+v"(d))
#define NOPG1(a,b,c,d) asm volatile("s_nop 1" : "+v"(a), "+v"(b), "+v"(c), "+v"(d))

// ---------------- fp32 -> fp16 convert (k,q,v,wk,wq,wv,wo), 16.78M elements ----
__global__ __launch_bounds__(256) void cvt_all(
    const float* __restrict__ k, const float* __restrict__ q, const float* __restrict__ v,
    const float* __restrict__ wk, const float* __restrict__ wq, const float* __restrict__ wv,
    const float* __restrict__ wo, unsigned short* __restrict__ dst) {
  const int i = (blockIdx.x * 256 + threadIdx.x) * 4;  // element idx, < 16777216
  const float* src; int off;
  if (i < 4194304)       { src = k;  off = 0; }
  else if (i < 8388608)  { src = q;  off = 4194304; }
  else if (i < 12582912) { src = v;  off = 8388608; }
  else if (i < 13631488) { src = wk; off = 12582912; }
  else if (i < 14680064) { src = wq; off = 13631488; }
  else if (i < 15728640) { src = wv; off = 14680064; }
  else                   { src = wo; off = 15728640; }
  float4 val = *(const float4*)(src + (i - off));
  ushort4 o;
  o.x = f2h(val.x); o.y = f2h(val.y); o.z = f2h(val.z); o.w = f2h(val.w);
  *(ushort4*)(dst + i) = o;
}

// ---------------- NT GEMM 128x128 tile, BK=32, M=4096,N=1024,K=1024 -----------
// Double-buffered LDS, counted vmcnt, one raw barrier per K-step.
// mode 0: fp16 out [B,H,S,64] (scaled) ; mode 1: fp16 out [B,H,64,S] (V^T) ; mode 2: fp32 [M,N]
DEV void gemm_body(const unsigned short* __restrict__ A, const unsigned short* __restrict__ W,
                   const float* __restrict__ bias, void* __restrict__ out, int mode,
                   float oscale) {
  __shared__ alignas(16) char lds_a[2][8192];
  __shared__ alignas(16) char lds_b[2][8192];
  const int t = threadIdx.x;
  const int l = t & 63, g = l >> 4, c = l & 15, w = t >> 6;
  const int wr = w >> 1, wc = w & 1;
  const int m0 = blockIdx.y << 7, n0 = blockIdx.x << 7;

  f32x4 acc[4][4] = {};

  // staging: tile row = 64B = 4x16B slots; swizzle slot ^= (row&3)
  const int i0 = t, i1 = t + 256;
  const int ar0 = i0 >> 2, as0 = (i0 & 3) ^ (ar0 & 3);
  const int ar1 = i1 >> 2, as1 = (i1 & 3) ^ (ar1 & 3);
  const unsigned short* ga0 = A + (long)(m0 + ar0) * 1024 + as0 * 8;
  const unsigned short* ga1 = A + (long)(m0 + ar1) * 1024 + as1 * 8;
  const unsigned short* gb0 = W + (long)(n0 + ar0) * 1024 + as0 * 8;
  const unsigned short* gb1 = W + (long)(n0 + ar1) * 1024 + as1 * 8;
  const int lo0 = i0 * 16, lo1 = i1 * 16;

  int aoff[4], boff[4];
#pragma unroll
  for (int i = 0; i < 4; i++) {
    const int ra = (wr << 6) + (i << 4) + c;
    aoff[i] = ra * 64 + ((g << 4) ^ ((ra & 3) << 4));
    const int rb = (wc << 6) + (i << 4) + c;
    boff[i] = rb * 64 + ((g << 4) ^ ((rb & 3) << 4));
  }

  // prologue: stage kt=0 into buf 0
  gload16(ga0, lds_a[0] + lo0);
  gload16(ga1, lds_a[0] + lo1);
  gload16(gb0, lds_b[0] + lo0);
  gload16(gb1, lds_b[0] + lo1);

  for (int kt = 0; kt < 32; kt++) {
    const int cur = kt & 1;
    VMCNT0();                       // own buf[cur] loads landed (issued last iter)
    __builtin_amdgcn_s_barrier();   // everyone's landed; everyone done with buf[cur^1]
    if (kt + 1 < 32) {
      gload16(ga0 + ((kt + 1) << 5), lds_a[cur ^ 1] + lo0);
      gload16(ga1 + ((kt + 1) << 5), lds_a[cur ^ 1] + lo1);
      gload16(gb0 + ((kt + 1) << 5), lds_b[cur ^ 1] + lo0);
      gload16(gb1 + ((kt + 1) << 5), lds_b[cur ^ 1] + lo1);
    }
    u32x4 af[4], bf[4];
#pragma unroll
    for (int i = 0; i < 4; i++) af[i] = *(const u32x4*)(lds_a[cur] + aoff[i]);
#pragma unroll
    for (int j = 0; j < 4; j++) bf[j] = *(const u32x4*)(lds_b[cur] + boff[j]);
#pragma unroll
    for (int i = 0; i < 4; i++)
#pragma unroll
      for (int j = 0; j < 4; j++)
        mfma16(acc[i][j], af[i], bf[j]);
  }

  NOPG(acc[0][0], acc[0][1], acc[0][2], acc[0][3]);
  NOPG(acc[1][0], acc[1][1], acc[1][2], acc[1][3]);
  NOPG(acc[2][0], acc[2][1], acc[2][2], acc[2][3]);
  NOPG(acc[3][0], acc[3][1], acc[3][2], acc[3][3]);

  if (mode == 1) {  // V^T layout: pack 4 consecutive s per lane -> 8B store
#pragma unroll
    for (int j = 0; j < 4; j++) {
      const int n = n0 + (wc << 6) + (j << 4) + c;
      const float bb = bias[n];
      const int h = n >> 6, d = n & 63;
#pragma unroll
      for (int i = 0; i < 4; i++) {
        const int m = m0 + (wr << 6) + (i << 4) + (g << 2);
        const int b = m >> 11, s = m & 2047;
        ushort4 o;
        o.x = f2h(acc[i][j][0] + bb);
        o.y = f2h(acc[i][j][1] + bb);
        o.z = f2h(acc[i][j][2] + bb);
        o.w = f2h(acc[i][j][3] + bb);
        *(ushort4*)&((unsigned short*)out)[((long)((b << 4) + h) * 64 + d) * 2048 + s] = o;
      }
    }
  } else {
#pragma unroll
    for (int j = 0; j < 4; j++) {
      const int n = n0 + (wc << 6) + (j << 4) + c;
      const float bb = bias[n];
#pragma unroll
      for (int i = 0; i < 4; i++) {
#pragma unroll
        for (int r = 0; r < 4; r++) {
          const int m = m0 + (wr << 6) + (i << 4) + (g << 2) + r;
          const float val = (acc[i][j][r] + bb) * oscale;
          if (mode == 2) {
            ((float*)out)[(long)m * 1024 + n] = val;
          } else {
            const int b = m >> 11, s = m & 2047;
            const int h = n >> 6, d = n & 63;
            ((unsigned short*)out)[((long)((b << 4) + h) * 2048 + s) * 64 + d] = f2h(val);
          }
        }
      }
    }
  }
}

__global__ __launch_bounds__(256) void gemm_proj(
    const unsigned short* kb, const unsigned short* qb, const unsigned short* vb,
    const unsigned short* wkb, const unsigned short* wqb, const unsigned short* wvb,
    const float* bk, const float* bq, const float* bvv,
    unsigned short* Kp, unsigned short* Qp, unsigned short* VpT) {
  const int z = blockIdx.z;
  const unsigned short* A = (z == 0) ? kb : (z == 1) ? qb : vb;
  const unsigned short* W = (z == 0) ? wkb : (z == 1) ? wqb : wvb;
  const float* bias = (z == 0) ? bk : (z == 1) ? bq : bvv;
  void* out = (z == 0) ? (void*)Kp : (z == 1) ? (void*)Qp : (void*)VpT;
  // Q pre-scaled by 8*log2(e): softmax then uses exp2(s - m) with no per-score muls.
  const float sc = (z == 1) ? 11.5415603271f : 1.0f;
  gemm_body(A, W, bias, out, (z == 2) ? 1 : 0, sc);
}

__global__ __launch_bounds__(256) void gemm_out(
    const unsigned short* A, const unsigned short* W, const float* bias, float* out) {
  gemm_body(A, W, bias, out, 2, 1.0f);
}

// ---------------- flash attention ---------------------------------------------
// One q-tile (64 rows) per block; grid = (bh=32, rank=32), qt = 31-rank so the
// longest blocks dispatch first (LPT): dynamic backfill keeps ~4 blocks/CU.
// K/V double-buffered; 1 raw barrier + counted vmcnt per tile iteration.
__global__ __launch_bounds__(256) void attn_kernel(
    const unsigned short* __restrict__ Qp, const unsigned short* __restrict__ Kp,
    const unsigned short* __restrict__ VpT, unsigned short* __restrict__ O) {
  __shared__ alignas(16) char lds_k[2][8192];  // K tile [64 kv][64 d], swizzled
  __shared__ alignas(16) char lds_v[2][8192];  // V^T tile [64 d][64 kv], swizzled
  __shared__ alignas(16) char lds_p[8192];     // per-wave P [16 q][64 kv], swizzled

  const int t = threadIdx.x;
  const int l = t & 63, g = l >> 4, c = l & 15, w = t >> 6;
  const int bh = blockIdx.x;
  const int qt = 31 - (int)blockIdx.y;         // longest first (LPT)
  const int q0 = qt << 6;
  const int qrow = q0 + (w << 4);

  // staging: 128B rows = 8x16B slots; swizzle slot ^= (row&7)
  const int i0 = t, i1 = t + 256;
  const int r0 = i0 >> 3, s0 = (i0 & 7) ^ (r0 & 7);
  const int r1 = i1 >> 3, s1 = (i1 & 7) ^ (r1 & 7);
  const unsigned short* gk0 = Kp + ((long)bh * 2048 + r0) * 64 + s0 * 8;
  const unsigned short* gk1 = Kp + ((long)bh * 2048 + r1) * 64 + s1 * 8;
  const unsigned short* gv0 = VpT + ((long)bh * 64 + r0) * 2048 + s0 * 8;
  const unsigned short* gv1 = VpT + ((long)bh * 64 + r1) * 2048 + s1 * 8;
  const int lo0 = i0 * 16, lo1 = i1 * 16;

  int koff[4][2];
#pragma unroll
  for (int j = 0; j < 4; j++)
#pragma unroll
    for (int ks = 0; ks < 2; ks++) {
      const int row = (j << 4) + c;
      koff[j][ks] = row * 128 + (((ks << 6) + (g << 4)) ^ ((row & 7) << 4));
    }
  const int poff0 = (w << 11) + c * 128 + (((g << 4)) ^ ((c & 7) << 4));
  const int poff1 = (w << 11) + c * 128 + ((64 + (g << 4)) ^ ((c & 7) << 4));

  const int b = bh >> 4, h = bh & 15;

  const unsigned short* qbase = Qp + ((long)bh * 2048 + qrow + c) * 64 + g * 8;
  const u32x4 aq0 = *(const u32x4*)qbase;
  const u32x4 aq1 = *(const u32x4*)(qbase + 32);

  f32x4 oacc[4] = {};
  float mrun[4] = {-1e30f, -1e30f, -1e30f, -1e30f};
  float lrun[4] = {0.f, 0.f, 0.f, 0.f};

  const int ntiles = qt + 1;

  // prologue: stage tile 0 into buf 0
  gload16(gk0, lds_k[0] + lo0);
  gload16(gk1, lds_k[0] + lo1);
  gload16(gv0, lds_v[0] + lo0);
  gload16(gv1, lds_v[0] + lo1);

  for (int tt = 0; tt < ntiles; tt++) {
    const int cur = tt & 1;
    VMCNT0();                       // own buf[cur] loads landed
    __builtin_amdgcn_s_barrier();   // all landed; all done reading buf[cur^1]
    if (tt + 1 < ntiles) {
      const long kvn = (long)(tt + 1) << 6;
      gload16(gk0 + kvn * 64, lds_k[cur ^ 1] + lo0);
      gload16(gk1 + kvn * 64, lds_k[cur ^ 1] + lo1);
      gload16(gv0 + kvn,      lds_v[cur ^ 1] + lo0);
      gload16(gv1 + kvn,      lds_v[cur ^ 1] + lo1);
    }

    f32x4 sacc[4] = {};
    NOPG1(sacc[0], sacc[1], sacc[2], sacc[3]);
    __builtin_amdgcn_s_setprio(1);
#pragma unroll
    for (int j = 0; j < 4; j++) {
      u32x4 bk0 = *(const u32x4*)(lds_k[cur] + koff[j][0]);
      u32x4 bk1 = *(const u32x4*)(lds_k[cur] + koff[j][1]);
      mfma16(sacc[j], aq0, bk0);
      mfma16(sacc[j], aq1, bk1);
    }
    __builtin_amdgcn_s_setprio(0);
    NOPG(sacc[0], sacc[1], sacc[2], sacc[3]);

    const int kv0 = tt << 6;
    const bool diag = (tt == qt);
#pragma unroll
    for (int r = 0; r < 4; r++) {
      float v0 = sacc[0][r];
      float v1 = sacc[1][r];
      float v2 = sacc[2][r];
      float v3 = sacc[3][r];
      if (diag) {                   // uniform branch: causal mask, diagonal tile only
        const int qg = qrow + (g << 2) + r;
        if (kv0 + c      > qg) v0 = -1e30f;
        if (kv0 + 16 + c > qg) v1 = -1e30f;
        if (kv0 + 32 + c > qg) v2 = -1e30f;
        if (kv0 + 48 + c > qg) v3 = -1e30f;
      }
      float mx = fmaxf(fmaxf(v0, v1), fmaxf(v2, v3));
      mx = fmaxf(mx, __shfl_xor(mx, 1));
      mx = fmaxf(mx, __shfl_xor(mx, 2));
      mx = fmaxf(mx, __shfl_xor(mx, 4));
      mx = fmaxf(mx, __shfl_xor(mx, 8));
      const float mnew = fmaxf(mrun[r], mx);
      const float corr = exp2f(mrun[r] - mnew);
      const float p0 = exp2f(v0 - mnew);
      const float p1 = exp2f(v1 - mnew);
      const float p2 = exp2f(v2 - mnew);
      const float p3 = exp2f(v3 - mnew);
      lrun[r] = lrun[r] * corr + (p0 + p1 + p2 + p3);   // per-lane partial; reduce at end
      mrun[r] = mnew;
      oacc[0][r] *= corr; oacc[1][r] *= corr; oacc[2][r] *= corr; oacc[3][r] *= corr;
      const int prow = (g << 2) + r;
      char* pb = lds_p + (w << 11) + prow * 128;
      const int sw = (prow & 7) << 4;
      *(unsigned short*)(pb + (((c << 1)     ) ^ sw)) = f2h(p0);
      *(unsigned short*)(pb + (((c << 1) + 32) ^ sw)) = f2h(p1);
      *(unsigned short*)(pb + (((c << 1) + 64) ^ sw)) = f2h(p2);
      *(unsigned short*)(pb + (((c << 1) + 96) ^ sw)) = f2h(p3);
    }

    NOPG1(oacc[0], oacc[1], oacc[2], oacc[3]);
    u32x4 ap0 = *(const u32x4*)(lds_p + poff0);
    u32x4 ap1 = *(const u32x4*)(lds_p + poff1);
    __builtin_amdgcn_s_setprio(1);
#pragma unroll
    for (int jd = 0; jd < 4; jd++) {
      u32x4 bv0 = *(const u32x4*)(lds_v[cur] + koff[jd][0]);
      u32x4 bv1 = *(const u32x4*)(lds_v[cur] + koff[jd][1]);
      mfma16(oacc[jd], ap0, bv0);
      mfma16(oacc[jd], ap1, bv1);
    }
    __builtin_amdgcn_s_setprio(0);
  }

  NOPG(oacc[0], oacc[1], oacc[2], oacc[3]);
#pragma unroll
  for (int r = 0; r < 4; r++) {
    float lsum = lrun[r];
    lsum += __shfl_xor(lsum, 1);
    lsum += __shfl_xor(lsum, 2);
    lsum += __shfl_xor(lsum, 4);
    lsum += __shfl_xor(lsum, 8);
    const float inv = 1.0f / lsum;
    const long mrow = (long)b * 2048 + q0 + (w << 4) + (g << 2) + r;
#pragma unroll
    for (int jd = 0; jd < 4; jd++)
      O[mrow * 1024 + (h << 6) + (jd << 4) + c] = f2h(oacc[jd][r] * inv);
  }
}

// ---------------- launch ------------------------------------------------------
extern "C" void kernel_launch(void* const* d_in, const int* in_sizes, int n_in,
                              void* d_out, int out_size, void* d_ws, size_t ws_size,
                              hipStream_t stream) {
  (void)in_sizes; (void)n_in; (void)out_size; (void)ws_size;
  const float* kin = (const float*)d_in[0];
  const float* qin = (const float*)d_in[1];
  const float* vin = (const float*)d_in[2];
  const float* wk  = (const float*)d_in[4];
  const float* bk  = (const float*)d_in[5];
  const float* wq  = (const float*)d_in[6];
  const float* bq  = (const float*)d_in[7];
  const float* wv  = (const float*)d_in[8];
  const float* bv  = (const float*)d_in[9];
  const float* wo  = (const float*)d_in[10];
  const float* bo  = (const float*)d_in[11];

  unsigned short* ws  = (unsigned short*)d_ws;   // 64 MiB used
  unsigned short* kb  = ws;                       // fp16 inputs
  unsigned short* qb  = ws + 4194304;
  unsigned short* vb  = ws + 8388608;
  unsigned short* wkb = ws + 12582912;
  unsigned short* wqb = ws + 13631488;
  unsigned short* wvb = ws + 14680064;
  unsigned short* wob = ws + 15728640;
  unsigned short* Kp  = ws + 16777216;            // [B,H,S,64]
  unsigned short* Qp  = ws + 20971520;            // [B,H,S,64], pre-scaled by 8*log2e
  unsigned short* VpT = ws + 25165824;            // [B,H,64,S]
  unsigned short* Oo  = ws + 29360128;            // [B,S,D]

  cvt_all<<<16384, 256, 0, stream>>>(kin, qin, vin, wk, wq, wv, wo, ws);
  gemm_proj<<<dim3(8, 32, 3), 256, 0, stream>>>(kb, qb, vb, wkb, wqb, wvb,
                                                bk, bq, bv, Kp, Qp, VpT);
  attn_kernel<<<dim3(32, 32), 256, 0, stream>>>(Qp, Kp, VpT, Oo);
  gemm_out<<<dim3(8, 32), 256, 0, stream>>>(Oo, wob, bo, (float*)d_out);
}